// Round 1
// baseline (134.206 us; speedup 1.0000x reference)
//
#include <hip/hip_runtime.h>

// CustomMultiheadAttention on MI355X (gfx950).
// B=4 T=1024 S=1024 H=16 D=64 E=1024. Output fp32 [B,T,E].
//
// Pipeline:
//   proj_qkv : per-head Linear for Q (scaled by log2e/32), K, V(->transposed) as bf16
//   cvt_wout : Wout fp32 -> bf16
//   attn_fwd : scores^T = mfma(K,Q); P = exp2(scores); ctx = P@V / rowsum(P)
//              (no max-subtraction: |score| <~ 2.5 since scale is 1/32 -> safe in fp32)
//   out_proj : ctx(bf16) @ Wout^T + bout -> fp32
//
// Workspace layout (22 MB):
//   [0,8MB)   qs  bf16 [B*H, T, D]   (pre-scaled by log2(e)/sqrt(E))
//   [8,10MB)  kb  bf16 [H, S, D]
//   [10,12MB) vt  bf16 [H, D, S]     (V transposed so PV B-frags load contiguous)
//   [12,20MB) ctx bf16 [B*T, E]
//   [20,22MB) wb  bf16 [E, E]        (Wout)

typedef __attribute__((ext_vector_type(8))) short short8v;
typedef __attribute__((ext_vector_type(4))) short short4v;
typedef __attribute__((ext_vector_type(4))) float float4v;

#define MFMA_BF16(A, B, C) __builtin_amdgcn_mfma_f32_16x16x32_bf16(A, B, C, 0, 0, 0)

#if __has_builtin(__builtin_amdgcn_exp2f)
#define EXP2F(x) __builtin_amdgcn_exp2f(x)
#else
#define EXP2F(x) exp2f(x)
#endif

// log2(e) / sqrt(E) = 1.4426950408889634 / 32
#define QSCALE 0.045084220027780106f

__device__ __forceinline__ short f2bf(float f) {
  union { float f; unsigned u; } v; v.f = f;
  unsigned r = v.u + 0x7FFFu + ((v.u >> 16) & 1u);   // RNE; inputs are finite
  return (short)(r >> 16);
}

// ---------------------------------------------------------------------------
// Kernel 1: per-head Q/K/V projections via MFMA.
// Wave-tasks: [0,4096) Q tiles (bh, t-tile16); [4096,5120) K; [5120,6144) V.
// A = 16 rows of X (fp32->bf16 on the fly), B = W^T (lane reads W[n][k] contiguous).
// ---------------------------------------------------------------------------
__global__ __launch_bounds__(256) void proj_qkv(
    const float* __restrict__ query, const float* __restrict__ para,
    const float* __restrict__ Wq, const float* __restrict__ bq,
    const float* __restrict__ Wk, const float* __restrict__ bk,
    const float* __restrict__ Wv, const float* __restrict__ bv,
    short* __restrict__ qs, short* __restrict__ kb, short* __restrict__ vt) {
  const int task = blockIdx.x * 4 + (threadIdx.x >> 6);
  const int lane = threadIdx.x & 63;
  const int g = lane >> 4, c = lane & 15;

  const float* W;
  const float* bias;
  const float* xrow;
  int type, h, tile, bh = 0;
  if (task < 4096) {
    type = 0; bh = task >> 6; tile = task & 63; h = bh & 15;
    xrow = query + ((bh >> 4) * 1024 + tile * 16 + c) * 1024 + h * 64;
    W = Wq; bias = bq;
  } else if (task < 5120) {
    int idx = task - 4096;
    type = 1; h = idx >> 6; tile = idx & 63;
    xrow = para + (tile * 16 + c) * 1024 + h * 64;
    W = Wk; bias = bk;
  } else {
    int idx = task - 5120;
    type = 2; h = idx >> 6; tile = idx & 63;
    xrow = para + (tile * 16 + c) * 1024 + h * 64;
    W = Wv; bias = bv;
  }

  // A fragments: rows of X. lane -> m = c, k = kh*32 + 8g + j (contiguous)
  short8v af[2];
#pragma unroll
  for (int kh = 0; kh < 2; ++kh) {
    const float* xp = xrow + kh * 32 + g * 8;
    float4v x0 = *(const float4v*)xp;
    float4v x1 = *(const float4v*)(xp + 4);
    af[kh] = (short8v){ f2bf(x0.x), f2bf(x0.y), f2bf(x0.z), f2bf(x0.w),
                        f2bf(x1.x), f2bf(x1.y), f2bf(x1.z), f2bf(x1.w) };
  }

#pragma unroll
  for (int dn = 0; dn < 4; ++dn) {   // output-d tiles of 16
    float4v acc = (float4v){0.f, 0.f, 0.f, 0.f};
#pragma unroll
    for (int kh = 0; kh < 2; ++kh) {
      const float* wp = W + (dn * 16 + c) * 64 + kh * 32 + g * 8;  // W[n][k]
      float4v w0 = *(const float4v*)wp;
      float4v w1 = *(const float4v*)(wp + 4);
      short8v bfr = (short8v){ f2bf(w0.x), f2bf(w0.y), f2bf(w0.z), f2bf(w0.w),
                               f2bf(w1.x), f2bf(w1.y), f2bf(w1.z), f2bf(w1.w) };
      acc = MFMA_BF16(af[kh], bfr, acc);
    }
    const float bc = bias[dn * 16 + c];
    if (type == 0) {
#pragma unroll
      for (int r = 0; r < 4; ++r) {
        const int t = tile * 16 + 4 * g + r;
        qs[(bh * 1024 + t) * 64 + dn * 16 + c] = f2bf((acc[r] + bc) * QSCALE);
      }
    } else if (type == 1) {
#pragma unroll
      for (int r = 0; r < 4; ++r) {
        const int s = tile * 16 + 4 * g + r;
        kb[(h * 1024 + s) * 64 + dn * 16 + c] = f2bf(acc[r] + bc);
      }
    } else {
      // transposed store: vt[h][d][s], rows s = tile*16+4g+r consecutive -> 8B store
      short4v pk = (short4v){ f2bf(acc[0] + bc), f2bf(acc[1] + bc),
                              f2bf(acc[2] + bc), f2bf(acc[3] + bc) };
      *(short4v*)(vt + (h * 64 + dn * 16 + c) * 1024 + tile * 16 + 4 * g) = pk;
    }
  }
}

// ---------------------------------------------------------------------------
// Kernel 2: Wout fp32 -> bf16
// ---------------------------------------------------------------------------
__global__ __launch_bounds__(256) void cvt_wout(const float* __restrict__ wsrc,
                                                short* __restrict__ wdst) {
  const int i = (blockIdx.x * 256 + threadIdx.x) * 8;
  float4v x0 = *(const float4v*)(wsrc + i);
  float4v x1 = *(const float4v*)(wsrc + i + 4);
  short8v v = (short8v){ f2bf(x0.x), f2bf(x0.y), f2bf(x0.z), f2bf(x0.w),
                         f2bf(x1.x), f2bf(x1.y), f2bf(x1.z), f2bf(x1.w) };
  *(short8v*)(wdst + i) = v;
}

// ---------------------------------------------------------------------------
// Kernel 3: attention. 512 wgs (bh, t-tile128) x 4 waves (32 t-rows each).
// Swapped QK^T: sc = mfma(K_frag, Q_frag) -> lane holds P[s=4g+r(+16sm)][t=c(+16tn)],
// which packs r-consecutively into per-wave LDS P-tile [t][s] as 8B writes, and
// reads back as contiguous b128 A-frags for PV.
// ---------------------------------------------------------------------------
__global__ __launch_bounds__(256) void attn_fwd(
    const short* __restrict__ qs, const short* __restrict__ kb,
    const short* __restrict__ vt, short* __restrict__ ctx) {
  __shared__ __align__(16) short plds[4][32][40];   // per-wave [t_local][s_local+pad]
  const int w = threadIdx.x >> 6;
  const int lane = threadIdx.x & 63;
  const int g = lane >> 4, c = lane & 15;
  const int bh = blockIdx.x >> 3;
  const int t0 = (blockIdx.x & 7) * 128 + w * 32;
  const int b = bh >> 4, h = bh & 15;

  const short* qbase = qs + (bh * 1024 + t0) * 64;
  const short* kbase = kb + h * 1024 * 64;
  const short* vbase = vt + h * 64 * 1024;

  // Q fragments (B-operand): lane -> n = c (t), k = kh*32 + 8g + j
  short8v qf[2][2];
#pragma unroll
  for (int tn = 0; tn < 2; ++tn)
#pragma unroll
    for (int kh = 0; kh < 2; ++kh)
      qf[tn][kh] = *(const short8v*)(qbase + (tn * 16 + c) * 64 + kh * 32 + g * 8);

  float4v cacc[2][4];
#pragma unroll
  for (int mt = 0; mt < 2; ++mt)
#pragma unroll
    for (int nt = 0; nt < 4; ++nt)
      cacc[mt][nt] = (float4v){0.f, 0.f, 0.f, 0.f};
  float denp[2] = {0.f, 0.f};

  // K prefetch pipeline (1 tile ahead)
  short8v kf[2][2];
#pragma unroll
  for (int sm = 0; sm < 2; ++sm)
#pragma unroll
    for (int kh = 0; kh < 2; ++kh)
      kf[sm][kh] = *(const short8v*)(kbase + (sm * 16 + c) * 64 + kh * 32 + g * 8);

  for (int s0 = 0; s0 < 1024; s0 += 32) {
    const int s1 = (s0 + 32) & 1023;   // wrap: last prefetch is unused but valid
    short8v kn[2][2];
#pragma unroll
    for (int sm = 0; sm < 2; ++sm)
#pragma unroll
      for (int kh = 0; kh < 2; ++kh)
        kn[sm][kh] = *(const short8v*)(kbase + (s1 + sm * 16 + c) * 64 + kh * 32 + g * 8);

    // V fragments (B-operand), from transposed V: contiguous in s
    short8v vf[4];
#pragma unroll
    for (int nt = 0; nt < 4; ++nt)
      vf[nt] = *(const short8v*)(vbase + (nt * 16 + c) * 1024 + s0 + g * 8);

    // scores^T tiles + exp2 + denom partials + pack to LDS
#pragma unroll
    for (int sm = 0; sm < 2; ++sm)
#pragma unroll
      for (int tn = 0; tn < 2; ++tn) {
        float4v z = (float4v){0.f, 0.f, 0.f, 0.f};
        z = MFMA_BF16(kf[sm][0], qf[tn][0], z);
        z = MFMA_BF16(kf[sm][1], qf[tn][1], z);
        const float p0 = EXP2F(z[0]);
        const float p1 = EXP2F(z[1]);
        const float p2 = EXP2F(z[2]);
        const float p3 = EXP2F(z[3]);
        denp[tn] += (p0 + p1) + (p2 + p3);
        short4v pk = (short4v){ f2bf(p0), f2bf(p1), f2bf(p2), f2bf(p3) };
        // t_local = tn*16 + c ; s_local = sm*16 + 4g + r (r-consecutive, 8B store)
        *(short4v*)&plds[w][tn * 16 + c][sm * 16 + 4 * g] = pk;
      }

    asm volatile("" ::: "memory");   // keep ds_write -> ds_read ordering (same wave)

    // P A-fragments: lane -> m = c (t), k = 8g + j (s)
    short8v pa[2];
#pragma unroll
    for (int mt = 0; mt < 2; ++mt)
      pa[mt] = *(const short8v*)&plds[w][mt * 16 + c][g * 8];

#pragma unroll
    for (int mt = 0; mt < 2; ++mt)
#pragma unroll
      for (int nt = 0; nt < 4; ++nt)
        cacc[mt][nt] = MFMA_BF16(pa[mt], vf[nt], cacc[mt][nt]);

    asm volatile("" ::: "memory");   // next iter's writes must not pass these reads

#pragma unroll
    for (int sm = 0; sm < 2; ++sm)
#pragma unroll
      for (int kh = 0; kh < 2; ++kh)
        kf[sm][kh] = kn[sm][kh];
  }

  // full row-denominators: lane's partials cover s with (s mod 16) in [4g,4g+3];
  // xor over lane bits 4,5 sums the four g-groups.
#pragma unroll
  for (int tn = 0; tn < 2; ++tn) {
    denp[tn] += __shfl_xor(denp[tn], 16);
    denp[tn] += __shfl_xor(denp[tn], 32);
  }

  const int orow0 = b * 1024 + t0;
#pragma unroll
  for (int mt = 0; mt < 2; ++mt) {
    float inv[4];
#pragma unroll
    for (int r = 0; r < 4; ++r)
      inv[r] = 1.0f / __shfl(denp[mt], 4 * g + r);  // den for t = mt*16 + 4g + r
#pragma unroll
    for (int nt = 0; nt < 4; ++nt) {
#pragma unroll
      for (int r = 0; r < 4; ++r) {
        const int row = orow0 + mt * 16 + 4 * g + r;
        ctx[row * 1024 + h * 64 + nt * 16 + c] = f2bf(cacc[mt][nt][r] * inv[r]);
      }
    }
  }
}

// ---------------------------------------------------------------------------
// Kernel 4: out = ctx(bf16) @ Wout^T + bout, fp32 out.
// 512 wgs: 32 m-tiles(128) x 16 n-tiles(64); wave = 32x64 strip; K prefetch 1 ahead.
// ---------------------------------------------------------------------------
__global__ __launch_bounds__(256) void out_proj(
    const short* __restrict__ ctx, const short* __restrict__ wb,
    const float* __restrict__ bout, float* __restrict__ out) {
  const int w = threadIdx.x >> 6;
  const int lane = threadIdx.x & 63;
  const int g = lane >> 4, c = lane & 15;
  const int m0 = (blockIdx.x & 31) * 128 + w * 32;
  const int n0 = (blockIdx.x >> 5) * 64;

  float4v acc[2][4];
#pragma unroll
  for (int mt = 0; mt < 2; ++mt)
#pragma unroll
    for (int nt = 0; nt < 4; ++nt)
      acc[mt][nt] = (float4v){0.f, 0.f, 0.f, 0.f};

  short8v a[2], bb[4], an[2], bn[4];
#pragma unroll
  for (int mt = 0; mt < 2; ++mt)
    a[mt] = *(const short8v*)(ctx + (m0 + mt * 16 + c) * 1024 + g * 8);
#pragma unroll
  for (int nt = 0; nt < 4; ++nt)
    bb[nt] = *(const short8v*)(wb + (n0 + nt * 16 + c) * 1024 + g * 8);

  for (int kk = 0; kk < 1024; kk += 32) {
    const int k1 = (kk + 32) & 1023;
#pragma unroll
    for (int mt = 0; mt < 2; ++mt)
      an[mt] = *(const short8v*)(ctx + (m0 + mt * 16 + c) * 1024 + k1 + g * 8);
#pragma unroll
    for (int nt = 0; nt < 4; ++nt)
      bn[nt] = *(const short8v*)(wb + (n0 + nt * 16 + c) * 1024 + k1 + g * 8);
#pragma unroll
    for (int mt = 0; mt < 2; ++mt)
#pragma unroll
      for (int nt = 0; nt < 4; ++nt)
        acc[mt][nt] = MFMA_BF16(a[mt], bb[nt], acc[mt][nt]);
#pragma unroll
    for (int mt = 0; mt < 2; ++mt) a[mt] = an[mt];
#pragma unroll
    for (int nt = 0; nt < 4; ++nt) bb[nt] = bn[nt];
  }

  float bs[4];
#pragma unroll
  for (int nt = 0; nt < 4; ++nt) bs[nt] = bout[n0 + nt * 16 + c];

#pragma unroll
  for (int mt = 0; mt < 2; ++mt)
#pragma unroll
    for (int nt = 0; nt < 4; ++nt)
#pragma unroll
      for (int r = 0; r < 4; ++r)
        out[(m0 + mt * 16 + 4 * g + r) * 1024 + n0 + nt * 16 + c] =
            acc[mt][nt][r] + bs[nt];
}

// ---------------------------------------------------------------------------
extern "C" void kernel_launch(void* const* d_in, const int* in_sizes, int n_in,
                              void* d_out, int out_size, void* d_ws, size_t ws_size,
                              hipStream_t stream) {
  const float* query = (const float*)d_in[0];
  const float* para  = (const float*)d_in[1];
  const float* Wq = (const float*)d_in[2];
  const float* bq = (const float*)d_in[3];
  const float* Wk = (const float*)d_in[4];
  const float* bk = (const float*)d_in[5];
  const float* Wv = (const float*)d_in[6];
  const float* bv = (const float*)d_in[7];
  const float* Wout = (const float*)d_in[8];
  const float* bout = (const float*)d_in[9];
  float* out = (float*)d_out;

  char* ws = (char*)d_ws;
  short* qs  = (short*)(ws);                      // 8 MB
  short* kb  = (short*)(ws + (8u  << 20));        // 2 MB
  short* vt  = (short*)(ws + (10u << 20));        // 2 MB
  short* ctx = (short*)(ws + (12u << 20));        // 8 MB
  short* wb  = (short*)(ws + (20u << 20));        // 2 MB

  proj_qkv<<<dim3(1536), dim3(256), 0, stream>>>(query, para, Wq, bq, Wk, bk,
                                                 Wv, bv, qs, kb, vt);
  cvt_wout<<<dim3(512), dim3(256), 0, stream>>>(Wout, wb);
  attn_fwd<<<dim3(512), dim3(256), 0, stream>>>(qs, kb, vt, ctx);
  out_proj<<<dim3(512), dim3(256), 0, stream>>>(ctx, wb, bout, out);
}

// Round 3
// 71.430 us; speedup vs baseline: 1.8788x; 1.8788x over previous
//
#include <hip/hip_runtime.h>

// CustomMultiheadAttention on MI355X (gfx950).
// B=4 T=1024 S=1024 H=16 D=64 E=1024. Output fp32 [B,T,E].
//
//   proj_qkv : per-head Linear for Q (scaled by log2e/32), K, V(->transposed) bf16
//   cvt_wout : Wout fp32 -> bf16
//   attn_fwd : 512 blocks x 8 waves; K/V reg-staged to shared LDS (dbuf,
//              XOR-swizzled source, linear dest); swapped QK^T;
//              P = exp2(scores) (no max-subtraction: |score| <= ~2.5)
//   out_proj : ctx(bf16) @ Wout^T + bout, 128x64 block tile, reg-staged LDS dbuf
//
// Staging transport is register-based (global load -> ds_write): the ds_write
// data-depends on the load (vmcnt wait auto-inserted) and __syncthreads drains
// lgkmcnt, so double-buffer visibility is guaranteed by construction.
// (r2 used global_load_lds with __syncthreads as the only fence -> intermittent
//  stale chunks -> absmax 1.8e-2. Addressing/swizzles verified and kept as-is.)
//
// Workspace (22 MB):
//   [0,8MB) qs bf16 [B*H,T,D] | [8,10) kb [H,S,D] | [10,12) vt [H,D,S]
//   [12,20) ctx bf16 [B*T,E]  | [20,22) wb [E,E]

typedef __attribute__((ext_vector_type(8))) short short8v;
typedef __attribute__((ext_vector_type(4))) short short4v;
typedef __attribute__((ext_vector_type(4))) float float4v;

#define MFMA_BF16(A, B, C) __builtin_amdgcn_mfma_f32_16x16x32_bf16(A, B, C, 0, 0, 0)

#if __has_builtin(__builtin_amdgcn_exp2f)
#define EXP2F(x) __builtin_amdgcn_exp2f(x)
#else
#define EXP2F(x) exp2f(x)
#endif

#define QSCALE 0.045084220027780106f   // log2(e)/32

__device__ __forceinline__ short f2bf(float f) {
  union { float f; unsigned u; } v; v.f = f;
  unsigned r = v.u + 0x7FFFu + ((v.u >> 16) & 1u);
  return (short)(r >> 16);
}

// ---------------------------------------------------------------------------
// Kernel 1: per-head Q/K/V projections via MFMA (unchanged; passed in r1).
// ---------------------------------------------------------------------------
__global__ __launch_bounds__(256) void proj_qkv(
    const float* __restrict__ query, const float* __restrict__ para,
    const float* __restrict__ Wq, const float* __restrict__ bq,
    const float* __restrict__ Wk, const float* __restrict__ bk,
    const float* __restrict__ Wv, const float* __restrict__ bv,
    short* __restrict__ qs, short* __restrict__ kb, short* __restrict__ vt) {
  const int task = blockIdx.x * 4 + (threadIdx.x >> 6);
  const int lane = threadIdx.x & 63;
  const int g = lane >> 4, c = lane & 15;

  const float* W;
  const float* bias;
  const float* xrow;
  int type, h, tile, bh = 0;
  if (task < 4096) {
    type = 0; bh = task >> 6; tile = task & 63; h = bh & 15;
    xrow = query + ((bh >> 4) * 1024 + tile * 16 + c) * 1024 + h * 64;
    W = Wq; bias = bq;
  } else if (task < 5120) {
    int idx = task - 4096;
    type = 1; h = idx >> 6; tile = idx & 63;
    xrow = para + (tile * 16 + c) * 1024 + h * 64;
    W = Wk; bias = bk;
  } else {
    int idx = task - 5120;
    type = 2; h = idx >> 6; tile = idx & 63;
    xrow = para + (tile * 16 + c) * 1024 + h * 64;
    W = Wv; bias = bv;
  }

  short8v af[2];
#pragma unroll
  for (int kh = 0; kh < 2; ++kh) {
    const float* xp = xrow + kh * 32 + g * 8;
    float4v x0 = *(const float4v*)xp;
    float4v x1 = *(const float4v*)(xp + 4);
    af[kh] = (short8v){ f2bf(x0.x), f2bf(x0.y), f2bf(x0.z), f2bf(x0.w),
                        f2bf(x1.x), f2bf(x1.y), f2bf(x1.z), f2bf(x1.w) };
  }

#pragma unroll
  for (int dn = 0; dn < 4; ++dn) {
    float4v acc = (float4v){0.f, 0.f, 0.f, 0.f};
#pragma unroll
    for (int kh = 0; kh < 2; ++kh) {
      const float* wp = W + (dn * 16 + c) * 64 + kh * 32 + g * 8;
      float4v w0 = *(const float4v*)wp;
      float4v w1 = *(const float4v*)(wp + 4);
      short8v bfr = (short8v){ f2bf(w0.x), f2bf(w0.y), f2bf(w0.z), f2bf(w0.w),
                               f2bf(w1.x), f2bf(w1.y), f2bf(w1.z), f2bf(w1.w) };
      acc = MFMA_BF16(af[kh], bfr, acc);
    }
    const float bc = bias[dn * 16 + c];
    if (type == 0) {
#pragma unroll
      for (int r = 0; r < 4; ++r) {
        const int t = tile * 16 + 4 * g + r;
        qs[(bh * 1024 + t) * 64 + dn * 16 + c] = f2bf((acc[r] + bc) * QSCALE);
      }
    } else if (type == 1) {
#pragma unroll
      for (int r = 0; r < 4; ++r) {
        const int s = tile * 16 + 4 * g + r;
        kb[(h * 1024 + s) * 64 + dn * 16 + c] = f2bf(acc[r] + bc);
      }
    } else {
      short4v pk = (short4v){ f2bf(acc[0] + bc), f2bf(acc[1] + bc),
                              f2bf(acc[2] + bc), f2bf(acc[3] + bc) };
      *(short4v*)(vt + (h * 64 + dn * 16 + c) * 1024 + tile * 16 + 4 * g) = pk;
    }
  }
}

// ---------------------------------------------------------------------------
// Kernel 2: Wout fp32 -> bf16
// ---------------------------------------------------------------------------
__global__ __launch_bounds__(256) void cvt_wout(const float* __restrict__ wsrc,
                                                short* __restrict__ wdst) {
  const int i = (blockIdx.x * 256 + threadIdx.x) * 8;
  float4v x0 = *(const float4v*)(wsrc + i);
  float4v x1 = *(const float4v*)(wsrc + i + 4);
  short8v v = (short8v){ f2bf(x0.x), f2bf(x0.y), f2bf(x0.z), f2bf(x0.w),
                         f2bf(x1.x), f2bf(x1.y), f2bf(x1.z), f2bf(x1.w) };
  *(short8v*)(wdst + i) = v;
}

// ---------------------------------------------------------------------------
// Kernel 3: attention. 512 blocks (bh x ttile128) x 8 waves (16 t-rows each).
// K/V tiles (4KB each) reg-staged into shared LDS, double-buffered.
// LDS content layout (both bufs): LDS_K[r][ch] = K[r][ch ^ (r&7)]  (32r x 8ch)
//                                 LDS_V[d][ch] = V[d][ch ^ ((d>>1)&3)] (64d x 4ch)
// achieved with per-lane pre-swizzled SOURCE + linear lane*16 dest.
// ---------------------------------------------------------------------------
__global__ __launch_bounds__(512, 4) void attn_fwd(
    const short* __restrict__ qs, const short* __restrict__ kb,
    const short* __restrict__ vt, short* __restrict__ ctx) {
  __shared__ __align__(16) short kv[2][4096];      // per buf: K 4KB | V 4KB
  __shared__ __align__(16) short plds[8][16][40];  // per-wave P tile
  const int w = threadIdx.x >> 6;
  const int lane = threadIdx.x & 63;
  const int g = lane >> 4, c = lane & 15;
  const int bh = blockIdx.x >> 3;
  const int b = bh >> 4, h = bh & 15;
  const int t0 = (blockIdx.x & 7) * 128 + w * 16;

  // --- staging: per-lane pre-swizzled global source, per-lane linear LDS dest
  const char* kvsrc;
  int stepb;
  char* ldsdst;
  if (w < 4) {  // K rows r = w*8 + (lane>>3), source chunk = (lane&7) ^ (r&7)
    const int r = w * 8 + (lane >> 3);
    const int q = (lane & 7) ^ (lane >> 3);
    kvsrc = (const char*)(kb + h * 65536) + r * 128 + q * 16;
    stepb = 4096;
    ldsdst = (char*)&kv[0][0] + w * 1024 + lane * 16;
  } else {      // V rows d = (w-4)*16 + (lane>>2), source chunk = (lane&3) ^ ((d>>1)&3)
    const int d = (w - 4) * 16 + (lane >> 2);
    const int q = (lane & 3) ^ ((lane >> 3) & 3);
    kvsrc = (const char*)(vt + h * 65536) + d * 2048 + q * 16;
    stepb = 64;
    ldsdst = (char*)&kv[0][0] + 4096 + (w - 4) * 1024 + lane * 16;
  }

  // --- swizzled LDS read offsets (constant per lane) ---
  int koff[2][2];
#pragma unroll
  for (int sm = 0; sm < 2; ++sm)
#pragma unroll
    for (int kh = 0; kh < 2; ++kh)
      koff[sm][kh] = (sm * 16 + c) * 128 + (((kh * 4 + g) ^ (c & 7)) * 16);
  int voff[4];
#pragma unroll
  for (int nt = 0; nt < 4; ++nt)
    voff[nt] = 4096 + (nt * 16 + c) * 64 + ((g ^ ((c >> 1) & 3)) * 16);

  // Q fragments (B-operand): n=c (t), k=kh*32+8g+j
  const short* qbase = qs + (bh * 1024 + t0) * 64;
  short8v qf[2];
#pragma unroll
  for (int kh = 0; kh < 2; ++kh)
    qf[kh] = *(const short8v*)(qbase + c * 64 + kh * 32 + g * 8);

  float4v cacc[4];
#pragma unroll
  for (int nt = 0; nt < 4; ++nt) cacc[nt] = (float4v){0.f, 0.f, 0.f, 0.f};
  float denp = 0.f;

  // prologue: tile 0 -> buf 0
  short8v stg = *(const short8v*)kvsrc;
  *(short8v*)ldsdst = stg;

  const char* kv0 = (const char*)&kv[0][0];
  for (int i = 0; i < 32; ++i) {
    __syncthreads();           // buf(i&1) visible; everyone past reads of other buf
    if (i < 31)
      stg = *(const short8v*)(kvsrc + (i + 1) * stepb);  // issue early (T14)

    const char* kvb = kv0 + (i & 1) * 8192;
    short8v kf[2][2];
#pragma unroll
    for (int sm = 0; sm < 2; ++sm)
#pragma unroll
      for (int kh = 0; kh < 2; ++kh)
        kf[sm][kh] = *(const short8v*)(kvb + koff[sm][kh]);
    short8v vf[4];
#pragma unroll
    for (int nt = 0; nt < 4; ++nt)
      vf[nt] = *(const short8v*)(kvb + voff[nt]);

    // scores^T (s=4g+r+16sm, t=c) -> exp2 -> denom partial -> pack to LDS
#pragma unroll
    for (int sm = 0; sm < 2; ++sm) {
      float4v z = (float4v){0.f, 0.f, 0.f, 0.f};
      z = MFMA_BF16(kf[sm][0], qf[0], z);
      z = MFMA_BF16(kf[sm][1], qf[1], z);
      const float p0 = EXP2F(z[0]);
      const float p1 = EXP2F(z[1]);
      const float p2 = EXP2F(z[2]);
      const float p3 = EXP2F(z[3]);
      denp += (p0 + p1) + (p2 + p3);
      short4v pk = (short4v){ f2bf(p0), f2bf(p1), f2bf(p2), f2bf(p3) };
      *(short4v*)&plds[w][c][sm * 16 + 4 * g] = pk;
    }

    asm volatile("" ::: "memory");   // order P write -> P read (same wave)

    short8v pa = *(const short8v*)&plds[w][c][g * 8];  // m=c(t), k=8g+j(s)
#pragma unroll
    for (int nt = 0; nt < 4; ++nt)
      cacc[nt] = MFMA_BF16(pa, vf[nt], cacc[nt]);

    asm volatile("" ::: "memory");

    if (i < 31)   // write tile i+1 into the other buffer (safe after barrier i)
      *(short8v*)(ldsdst + ((i + 1) & 1) * 8192) = stg;
  }

  // row denominators: sum partials over lane bits 4-5 (g groups)
  denp += __shfl_xor(denp, 16);
  denp += __shfl_xor(denp, 32);

  const int orow0 = b * 1024 + t0;
  float inv[4];
#pragma unroll
  for (int r = 0; r < 4; ++r)
    inv[r] = 1.0f / __shfl(denp, 4 * g + r);   // den of t-row 4g+r
#pragma unroll
  for (int nt = 0; nt < 4; ++nt)
#pragma unroll
    for (int r = 0; r < 4; ++r) {
      const int row = orow0 + 4 * g + r;
      ctx[row * 1024 + h * 64 + nt * 16 + c] = f2bf(cacc[nt][r] * inv[r]);
    }
}

// ---------------------------------------------------------------------------
// Kernel 4: out = ctx(bf16) @ Wout^T + bout. 512 blocks (32 m x 16 n) x 8
// waves; block tile 128x64; A(8KB)/B(4KB) reg-staged LDS, double-buffered.
// LDS content: LDS_A[r][ch] = A[r][ch ^ ((r>>1)&3)] (128r x 4ch), same for B.
// ---------------------------------------------------------------------------
__global__ __launch_bounds__(512, 4) void out_proj(
    const short* __restrict__ ctx, const short* __restrict__ wb,
    const float* __restrict__ bout, float* __restrict__ out) {
  __shared__ __align__(16) short ab[2][6144];   // per buf: A 8KB | B 4KB
  const int w = threadIdx.x >> 6;
  const int lane = threadIdx.x & 63;
  const int g = lane >> 4, c = lane & 15;
  const int mblk = (blockIdx.x & 31) * 128;
  const int n0 = (blockIdx.x >> 5) * 64;

  // staging: rows of 64B (32 k-elems), 4 chunks; source chunk ^= (row>>1)&3
  const int srow = w * 16 + (lane >> 2);              // 0..127
  const int sq = (lane & 3) ^ ((lane >> 3) & 3);
  const char* asrc = (const char*)ctx + (mblk + srow) * 2048 + sq * 16;
  char* adst = (char*)&ab[0][0] + w * 1024 + lane * 16;
  const char* bsrc = (const char*)wb + (n0 + srow) * 2048 + sq * 16;  // w<4 only
  char* bdst = (char*)&ab[0][0] + 8192 + w * 1024 + lane * 16;

  const int sw = (g ^ ((c >> 1) & 3)) * 16;
  const int aoff = (w * 16 + c) * 64 + sw;
  int boff[4];
#pragma unroll
  for (int nt = 0; nt < 4; ++nt)
    boff[nt] = 8192 + (nt * 16 + c) * 64 + sw;

  float4v acc[4];
#pragma unroll
  for (int nt = 0; nt < 4; ++nt) acc[nt] = (float4v){0.f, 0.f, 0.f, 0.f};

  // prologue: k-tile 0 -> buf 0
  short8v sa = *(const short8v*)asrc;
  short8v sb = (short8v){0, 0, 0, 0, 0, 0, 0, 0};
  if (w < 4) sb = *(const short8v*)bsrc;
  *(short8v*)adst = sa;
  if (w < 4) *(short8v*)bdst = sb;

  const char* ab0 = (const char*)&ab[0][0];
  for (int i = 0; i < 32; ++i) {
    __syncthreads();
    if (i < 31) {
      sa = *(const short8v*)(asrc + (i + 1) * 64);
      if (w < 4) sb = *(const short8v*)(bsrc + (i + 1) * 64);
    }
    const char* abb = ab0 + (i & 1) * 12288;
    short8v a = *(const short8v*)(abb + aoff);
    short8v bb[4];
#pragma unroll
    for (int nt = 0; nt < 4; ++nt)
      bb[nt] = *(const short8v*)(abb + boff[nt]);
#pragma unroll
    for (int nt = 0; nt < 4; ++nt)
      acc[nt] = MFMA_BF16(a, bb[nt], acc[nt]);
    if (i < 31) {
      *(short8v*)(adst + ((i + 1) & 1) * 12288) = sa;
      if (w < 4) *(short8v*)(bdst + ((i + 1) & 1) * 12288) = sb;
    }
  }

  float bs[4];
#pragma unroll
  for (int nt = 0; nt < 4; ++nt) bs[nt] = bout[n0 + nt * 16 + c];

  const int m0 = mblk + w * 16;
#pragma unroll
  for (int nt = 0; nt < 4; ++nt)
#pragma unroll
    for (int r = 0; r < 4; ++r)
      out[(m0 + 4 * g + r) * 1024 + n0 + nt * 16 + c] = acc[nt][r] + bs[nt];
}

// ---------------------------------------------------------------------------
extern "C" void kernel_launch(void* const* d_in, const int* in_sizes, int n_in,
                              void* d_out, int out_size, void* d_ws, size_t ws_size,
                              hipStream_t stream) {
  const float* query = (const float*)d_in[0];
  const float* para  = (const float*)d_in[1];
  const float* Wq = (const float*)d_in[2];
  const float* bq = (const float*)d_in[3];
  const float* Wk = (const float*)d_in[4];
  const float* bk = (const float*)d_in[5];
  const float* Wv = (const float*)d_in[6];
  const float* bv = (const float*)d_in[7];
  const float* Wout = (const float*)d_in[8];
  const float* bout = (const float*)d_in[9];
  float* out = (float*)d_out;

  char* ws = (char*)d_ws;
  short* qs  = (short*)(ws);                      // 8 MB
  short* kb  = (short*)(ws + (8u  << 20));        // 2 MB
  short* vt  = (short*)(ws + (10u << 20));        // 2 MB
  short* ctx = (short*)(ws + (12u << 20));        // 8 MB
  short* wb  = (short*)(ws + (20u << 20));        // 2 MB

  proj_qkv<<<dim3(1536), dim3(256), 0, stream>>>(query, para, Wq, bq, Wk, bk,
                                                 Wv, bv, qs, kb, vt);
  cvt_wout<<<dim3(512), dim3(256), 0, stream>>>(Wout, wb);
  attn_fwd<<<dim3(512), dim3(512), 0, stream>>>(qs, kb, vt, ctx);
  out_proj<<<dim3(512), dim3(512), 0, stream>>>(ctx, wb, bout, out);
}

// Round 5
// 71.186 us; speedup vs baseline: 1.8853x; 1.0034x over previous
//
#include <hip/hip_runtime.h>

// CustomMultiheadAttention on MI355X (gfx950).
// B=4 T=1024 S=1024 H=16 D=64 E=1024. Output fp32 [B,T,E].
//
//   proj_qkv : per-head Linear for Q (scaled by log2e/32), K, V(->transposed) bf16
//   cvt_wout : Wout fp32 -> bf16
//   attn_fwd : 512 blocks x 4 waves, 32 t-rows/wave; K/V reg-staged shared LDS
//              (dbuf, XOR-swizzled src, linear dest); swapped QK^T; P=exp2(z)
//              packed with scalar f2bf (r4's v_cvt_pk asm was the prime suspect
//              for the 3.7e-2 failure -- guide T12: "don't hand-write cvt_pk");
//              denominator via ones-MFMA (layout-consistent by construction);
//              XCD-swizzled grid (one head's t-tiles share an XCD L2).
//   out_proj : r3's exact known-good kernel (128x64 tile, 8 waves, LDS dbuf).
//
// Workspace (22 MB):
//   [0,8MB) qs bf16 [B*H,T,D] | [8,10) kb [H,S,D] | [10,12) vt [H,D,S]
//   [12,20) ctx bf16 [B*T,E]  | [20,22) wb [E,E]

typedef __attribute__((ext_vector_type(8))) short short8v;
typedef __attribute__((ext_vector_type(4))) short short4v;
typedef __attribute__((ext_vector_type(4))) float float4v;

#define MFMA_BF16(A, B, C) __builtin_amdgcn_mfma_f32_16x16x32_bf16(A, B, C, 0, 0, 0)

#if __has_builtin(__builtin_amdgcn_exp2f)
#define EXP2F(x) __builtin_amdgcn_exp2f(x)
#else
#define EXP2F(x) exp2f(x)
#endif

#define QSCALE 0.045084220027780106f   // log2(e)/32

__device__ __forceinline__ short f2bf(float f) {
  union { float f; unsigned u; } v; v.f = f;
  unsigned r = v.u + 0x7FFFu + ((v.u >> 16) & 1u);
  return (short)(r >> 16);
}

// ---------------------------------------------------------------------------
// Kernel 1: per-head Q/K/V projections via MFMA (unchanged; passed r1/r3).
// ---------------------------------------------------------------------------
__global__ __launch_bounds__(256) void proj_qkv(
    const float* __restrict__ query, const float* __restrict__ para,
    const float* __restrict__ Wq, const float* __restrict__ bq,
    const float* __restrict__ Wk, const float* __restrict__ bk,
    const float* __restrict__ Wv, const float* __restrict__ bv,
    short* __restrict__ qs, short* __restrict__ kb, short* __restrict__ vt) {
  const int task = blockIdx.x * 4 + (threadIdx.x >> 6);
  const int lane = threadIdx.x & 63;
  const int g = lane >> 4, c = lane & 15;

  const float* W;
  const float* bias;
  const float* xrow;
  int type, h, tile, bh = 0;
  if (task < 4096) {
    type = 0; bh = task >> 6; tile = task & 63; h = bh & 15;
    xrow = query + ((bh >> 4) * 1024 + tile * 16 + c) * 1024 + h * 64;
    W = Wq; bias = bq;
  } else if (task < 5120) {
    int idx = task - 4096;
    type = 1; h = idx >> 6; tile = idx & 63;
    xrow = para + (tile * 16 + c) * 1024 + h * 64;
    W = Wk; bias = bk;
  } else {
    int idx = task - 5120;
    type = 2; h = idx >> 6; tile = idx & 63;
    xrow = para + (tile * 16 + c) * 1024 + h * 64;
    W = Wv; bias = bv;
  }

  short8v af[2];
#pragma unroll
  for (int kh = 0; kh < 2; ++kh) {
    const float* xp = xrow + kh * 32 + g * 8;
    float4v x0 = *(const float4v*)xp;
    float4v x1 = *(const float4v*)(xp + 4);
    af[kh] = (short8v){ f2bf(x0.x), f2bf(x0.y), f2bf(x0.z), f2bf(x0.w),
                        f2bf(x1.x), f2bf(x1.y), f2bf(x1.z), f2bf(x1.w) };
  }

#pragma unroll
  for (int dn = 0; dn < 4; ++dn) {
    float4v acc = (float4v){0.f, 0.f, 0.f, 0.f};
#pragma unroll
    for (int kh = 0; kh < 2; ++kh) {
      const float* wp = W + (dn * 16 + c) * 64 + kh * 32 + g * 8;
      float4v w0 = *(const float4v*)wp;
      float4v w1 = *(const float4v*)(wp + 4);
      short8v bfr = (short8v){ f2bf(w0.x), f2bf(w0.y), f2bf(w0.z), f2bf(w0.w),
                               f2bf(w1.x), f2bf(w1.y), f2bf(w1.z), f2bf(w1.w) };
      acc = MFMA_BF16(af[kh], bfr, acc);
    }
    const float bc = bias[dn * 16 + c];
    if (type == 0) {
#pragma unroll
      for (int r = 0; r < 4; ++r) {
        const int t = tile * 16 + 4 * g + r;
        qs[(bh * 1024 + t) * 64 + dn * 16 + c] = f2bf((acc[r] + bc) * QSCALE);
      }
    } else if (type == 1) {
#pragma unroll
      for (int r = 0; r < 4; ++r) {
        const int s = tile * 16 + 4 * g + r;
        kb[(h * 1024 + s) * 64 + dn * 16 + c] = f2bf(acc[r] + bc);
      }
    } else {
      short4v pk = (short4v){ f2bf(acc[0] + bc), f2bf(acc[1] + bc),
                              f2bf(acc[2] + bc), f2bf(acc[3] + bc) };
      *(short4v*)(vt + (h * 64 + dn * 16 + c) * 1024 + tile * 16 + 4 * g) = pk;
    }
  }
}

// ---------------------------------------------------------------------------
// Kernel 2: Wout fp32 -> bf16
// ---------------------------------------------------------------------------
__global__ __launch_bounds__(256) void cvt_wout(const float* __restrict__ wsrc,
                                                short* __restrict__ wdst) {
  const int i = (blockIdx.x * 256 + threadIdx.x) * 8;
  float4v x0 = *(const float4v*)(wsrc + i);
  float4v x1 = *(const float4v*)(wsrc + i + 4);
  short8v v = (short8v){ f2bf(x0.x), f2bf(x0.y), f2bf(x0.z), f2bf(x0.w),
                         f2bf(x1.x), f2bf(x1.y), f2bf(x1.z), f2bf(x1.w) };
  *(short8v*)(wdst + i) = v;
}

// ---------------------------------------------------------------------------
// Kernel 3: attention. 512 blocks x 4 waves; wave owns 32 t-rows (tn=0,1).
// Grid XCD-swizzle: bh = blockIdx&63 so one head's 8 t-tiles share an XCD-L2.
// K/V tiles (4KB each) reg-staged into shared LDS, double-buffered:
//   LDS_K[r][ch] = K[r][ch ^ (r&7)]        (32 rows x 8 x 16B chunks)
//   LDS_V[d][ch] = V[d][ch ^ ((d>>1)&3)]   (64 rows x 4 x 16B chunks)
// Swapped QK^T: z = mfma(K,Q) -> lane(g,c) holds S[s=sm*16+4g+r][t=tn*16+c];
// P=exp2(z) scalar-packed (f2bf) into per-wave plds[tn][t][s], read back as
// b128 A-frags for PV. Denominator = mfma(pa, ones) in the matrix pipe
// (same-instruction layout consistency: inv[r] divides its own row).
// ---------------------------------------------------------------------------
__global__ __launch_bounds__(256, 4) void attn_fwd(
    const short* __restrict__ qs, const short* __restrict__ kb,
    const short* __restrict__ vt, short* __restrict__ ctx) {
  __shared__ __align__(16) short kv[2][4096];         // per buf: K 4KB | V 4KB
  __shared__ __align__(16) short plds[4][2][16][40];  // per-wave P tiles
  const int tid = threadIdx.x;
  const int w = tid >> 6;
  const int lane = tid & 63;
  const int g = lane >> 4, c = lane & 15;
  const int bh = blockIdx.x & 63;          // XCD-swizzle: bh%8 == XCD
  const int b = bh >> 4, h = bh & 15;
  const int t0 = (blockIdx.x >> 6) * 128 + w * 32;

  // --- staging: per-thread pre-swizzled global src, linear LDS dest ---
  const int kr = tid >> 3, kq = (tid & 7) ^ (kr & 7);
  const char* ksrc = (const char*)(kb + h * 65536) + kr * 128 + kq * 16;
  const int vd = tid >> 2, vq = (tid & 3) ^ ((vd >> 1) & 3);
  const char* vsrc = (const char*)(vt + h * 65536) + vd * 2048 + vq * 16;
  char* kdst = (char*)&kv[0][0] + tid * 16;
  char* vdst = (char*)&kv[0][0] + 4096 + tid * 16;

  // --- swizzled LDS read offsets (constant per lane) ---
  int koff[2][2];
#pragma unroll
  for (int sm = 0; sm < 2; ++sm)
#pragma unroll
    for (int kh = 0; kh < 2; ++kh)
      koff[sm][kh] = (sm * 16 + c) * 128 + (((kh * 4 + g) ^ (c & 7)) * 16);
  int voff[4];
#pragma unroll
  for (int nt = 0; nt < 4; ++nt)
    voff[nt] = 4096 + (nt * 16 + c) * 64 + ((g ^ ((c >> 1) & 3)) * 16);

  // Q fragments (B-operand): n=c -> t = t0+tn*16+c, k = kh*32+8g+j
  const short* qbase = qs + (bh * 1024 + t0) * 64;
  short8v qf[2][2];
#pragma unroll
  for (int tn = 0; tn < 2; ++tn)
#pragma unroll
    for (int kh = 0; kh < 2; ++kh)
      qf[tn][kh] = *(const short8v*)(qbase + (tn * 16 + c) * 64 + kh * 32 + g * 8);

  float4v cacc[2][4];
#pragma unroll
  for (int tn = 0; tn < 2; ++tn)
#pragma unroll
    for (int nt = 0; nt < 4; ++nt)
      cacc[tn][nt] = (float4v){0.f, 0.f, 0.f, 0.f};
  float4v dacc[2];
  dacc[0] = (float4v){0.f, 0.f, 0.f, 0.f};
  dacc[1] = (float4v){0.f, 0.f, 0.f, 0.f};
  const short obf = (short)0x3F80;   // bf16 1.0
  const short8v ones = (short8v){obf, obf, obf, obf, obf, obf, obf, obf};

  // prologue: tile 0 -> buf 0
  short8v sk = *(const short8v*)ksrc;
  short8v sv = *(const short8v*)vsrc;
  *(short8v*)kdst = sk;
  *(short8v*)vdst = sv;

  const char* kv0 = (const char*)&kv[0][0];
  for (int i = 0; i < 32; ++i) {
    __syncthreads();            // buf(i&1) ready; other buf free for writes
    if (i < 31) {               // issue next-tile loads early (latency hides)
      sk = *(const short8v*)(ksrc + (i + 1) * 4096);
      sv = *(const short8v*)(vsrc + (i + 1) * 64);
    }

    const char* kvb = kv0 + (i & 1) * 8192;
    short8v kf[2][2];
#pragma unroll
    for (int sm = 0; sm < 2; ++sm)
#pragma unroll
      for (int kh = 0; kh < 2; ++kh)
        kf[sm][kh] = *(const short8v*)(kvb + koff[sm][kh]);
    short8v vf[4];
#pragma unroll
    for (int nt = 0; nt < 4; ++nt)
      vf[nt] = *(const short8v*)(kvb + voff[nt]);

    // scores^T -> exp2 -> scalar pack into plds (known-good r1/r3 path)
#pragma unroll
    for (int sm = 0; sm < 2; ++sm)
#pragma unroll
      for (int tn = 0; tn < 2; ++tn) {
        float4v z = (float4v){0.f, 0.f, 0.f, 0.f};
        z = MFMA_BF16(kf[sm][0], qf[tn][0], z);
        z = MFMA_BF16(kf[sm][1], qf[tn][1], z);
        const float p0 = EXP2F(z[0]);
        const float p1 = EXP2F(z[1]);
        const float p2 = EXP2F(z[2]);
        const float p3 = EXP2F(z[3]);
        short4v pk = (short4v){ f2bf(p0), f2bf(p1), f2bf(p2), f2bf(p3) };
        *(short4v*)&plds[w][tn][c][sm * 16 + 4 * g] = pk;
      }

    asm volatile("" ::: "memory");   // order P write -> P read (same wave)

    short8v pa[2];
#pragma unroll
    for (int tn = 0; tn < 2; ++tn)
      pa[tn] = *(const short8v*)&plds[w][tn][c][g * 8];  // m=c(t), k=8g+j(s)

#pragma unroll
    for (int tn = 0; tn < 2; ++tn) {
#pragma unroll
      for (int nt = 0; nt < 4; ++nt)
        cacc[tn][nt] = MFMA_BF16(pa[tn], vf[nt], cacc[tn][nt]);
      dacc[tn] = MFMA_BF16(pa[tn], ones, dacc[tn]);   // rowsum(P), matrix pipe
    }

    asm volatile("" ::: "memory");

    if (i < 31) {   // write tile i+1 into the other buffer
      *(short8v*)(kdst + ((i + 1) & 1) * 8192) = sk;
      *(short8v*)(vdst + ((i + 1) & 1) * 8192) = sv;
    }
  }

  // epilogue: dacc[tn][r] = den(t = t0+tn*16+4g+r), same layout as cacc rows
  const int orow0 = b * 1024 + t0;
#pragma unroll
  for (int tn = 0; tn < 2; ++tn) {
    float inv[4];
#pragma unroll
    for (int r = 0; r < 4; ++r) inv[r] = 1.0f / dacc[tn][r];
#pragma unroll
    for (int nt = 0; nt < 4; ++nt)
#pragma unroll
      for (int r = 0; r < 4; ++r) {
        const int row = orow0 + tn * 16 + 4 * g + r;
        ctx[row * 1024 + h * 64 + nt * 16 + c] = f2bf(cacc[tn][nt][r] * inv[r]);
      }
  }
}

// ---------------------------------------------------------------------------
// Kernel 4: out = ctx(bf16) @ Wout^T + bout. r3's exact known-good kernel.
// 512 blocks (32 m x 16 n) x 8 waves; block tile 128x64; A(8KB)/B(4KB)
// reg-staged LDS, double-buffered. LDS content: [r][ch] = X[r][ch^((r>>1)&3)].
// ---------------------------------------------------------------------------
__global__ __launch_bounds__(512, 4) void out_proj(
    const short* __restrict__ ctx, const short* __restrict__ wb,
    const float* __restrict__ bout, float* __restrict__ out) {
  __shared__ __align__(16) short ab[2][6144];   // per buf: A 8KB | B 4KB
  const int w = threadIdx.x >> 6;
  const int lane = threadIdx.x & 63;
  const int g = lane >> 4, c = lane & 15;
  const int mblk = (blockIdx.x & 31) * 128;
  const int n0 = (blockIdx.x >> 5) * 64;

  // staging: rows of 64B (32 k-elems), 4 chunks; source chunk ^= (row>>1)&3
  const int srow = w * 16 + (lane >> 2);              // 0..127
  const int sq = (lane & 3) ^ ((lane >> 3) & 3);
  const char* asrc = (const char*)ctx + (mblk + srow) * 2048 + sq * 16;
  char* adst = (char*)&ab[0][0] + w * 1024 + lane * 16;
  const char* bsrc = (const char*)wb + (n0 + srow) * 2048 + sq * 16;  // w<4 only
  char* bdst = (char*)&ab[0][0] + 8192 + w * 1024 + lane * 16;

  const int sw = (g ^ ((c >> 1) & 3)) * 16;
  const int aoff = (w * 16 + c) * 64 + sw;
  int boff[4];
#pragma unroll
  for (int nt = 0; nt < 4; ++nt)
    boff[nt] = 8192 + (nt * 16 + c) * 64 + sw;

  float4v acc[4];
#pragma unroll
  for (int nt = 0; nt < 4; ++nt) acc[nt] = (float4v){0.f, 0.f, 0.f, 0.f};

  // prologue: k-tile 0 -> buf 0
  short8v sa = *(const short8v*)asrc;
  short8v sb = (short8v){0, 0, 0, 0, 0, 0, 0, 0};
  if (w < 4) sb = *(const short8v*)bsrc;
  *(short8v*)adst = sa;
  if (w < 4) *(short8v*)bdst = sb;

  const char* ab0 = (const char*)&ab[0][0];
  for (int i = 0; i < 32; ++i) {
    __syncthreads();
    if (i < 31) {
      sa = *(const short8v*)(asrc + (i + 1) * 64);
      if (w < 4) sb = *(const short8v*)(bsrc + (i + 1) * 64);
    }
    const char* abb = ab0 + (i & 1) * 12288;
    short8v a = *(const short8v*)(abb + aoff);
    short8v bb[4];
#pragma unroll
    for (int nt = 0; nt < 4; ++nt)
      bb[nt] = *(const short8v*)(abb + boff[nt]);
#pragma unroll
    for (int nt = 0; nt < 4; ++nt)
      acc[nt] = MFMA_BF16(a, bb[nt], acc[nt]);
    if (i < 31) {
      *(short8v*)(adst + ((i + 1) & 1) * 12288) = sa;
      if (w < 4) *(short8v*)(bdst + ((i + 1) & 1) * 12288) = sb;
    }
  }

  float bs[4];
#pragma unroll
  for (int nt = 0; nt < 4; ++nt) bs[nt] = bout[n0 + nt * 16 + c];

  const int m0 = mblk + w * 16;
#pragma unroll
  for (int nt = 0; nt < 4; ++nt)
#pragma unroll
    for (int r = 0; r < 4; ++r)
      out[(m0 + 4 * g + r) * 1024 + n0 + nt * 16 + c] = acc[nt][r] + bs[nt];
}

// ---------------------------------------------------------------------------
extern "C" void kernel_launch(void* const* d_in, const int* in_sizes, int n_in,
                              void* d_out, int out_size, void* d_ws, size_t ws_size,
                              hipStream_t stream) {
  const float* query = (const float*)d_in[0];
  const float* para  = (const float*)d_in[1];
  const float* Wq = (const float*)d_in[2];
  const float* bq = (const float*)d_in[3];
  const float* Wk = (const float*)d_in[4];
  const float* bk = (const float*)d_in[5];
  const float* Wv = (const float*)d_in[6];
  const float* bv = (const float*)d_in[7];
  const float* Wout = (const float*)d_in[8];
  const float* bout = (const float*)d_in[9];
  float* out = (float*)d_out;

  char* ws = (char*)d_ws;
  short* qs  = (short*)(ws);                      // 8 MB
  short* kb  = (short*)(ws + (8u  << 20));        // 2 MB
  short* vt  = (short*)(ws + (10u << 20));        // 2 MB
  short* ctx = (short*)(ws + (12u << 20));        // 8 MB
  short* wb  = (short*)(ws + (20u << 20));        // 2 MB

  proj_qkv<<<dim3(1536), dim3(256), 0, stream>>>(query, para, Wq, bq, Wk, bk,
                                                 Wv, bv, qs, kb, vt);
  cvt_wout<<<dim3(512), dim3(256), 0, stream>>>(Wout, wb);
  attn_fwd<<<dim3(512), dim3(256), 0, stream>>>(qs, kb, vt, ctx);
  out_proj<<<dim3(512), dim3(512), 0, stream>>>(ctx, wb, bout, out);
}